// Round 1
// baseline (50.206 us; speedup 1.0000x reference)
//
#include <hip/hip_runtime.h>
#include <math.h>

// YUMI left-arm FK: out[b,j] = T_static_0 Rz(a0) ... T_static_j Rz(aj), affine 4x4.
// Memory-bound: 117.4 MB out + 7.3 MB in => ~20 us floor at 6.3 TB/s.

struct Statics { float m[7][12]; };  // 3x4 row-major per joint (bottom row implicit 0,0,0,1)

__global__ __launch_bounds__(256) void fk_kernel(
    const float* __restrict__ eulers, float* __restrict__ out,
    Statics st, int B)
{
    __shared__ float ang[256 * 7];
    const int b0 = blockIdx.x * 256;

    // Coalesced staging of input angles into LDS.
    {
        int nb = B - b0; if (nb > 256) nb = 256;
        const int nval = nb * 7;
        for (int k = threadIdx.x; k < nval; k += 256)
            ang[k] = eulers[(size_t)b0 * 7 + k];
    }
    __syncthreads();

    const int b = b0 + (int)threadIdx.x;
    if (b >= B) return;
    const float* a = &ang[threadIdx.x * 7];  // stride 7 floats: coprime w/ 32 banks -> conflict-free

    // Accumulator T: 3x4 affine, init identity.
    float T[12] = {1.f,0.f,0.f,0.f, 0.f,1.f,0.f,0.f, 0.f,0.f,1.f,0.f};
    float* o = out + (size_t)b * 112;

    #pragma unroll
    for (int j = 0; j < 7; ++j) {
        float s, c;
        __sincosf(a[j], &s, &c);
        const float* S = st.m[j];  // kernarg-resident constants (s_load after unroll)

        // D = S @ Rz(a): only columns 0,1 mix; cols 2,3 pass through.
        float D[12];
        #pragma unroll
        for (int r = 0; r < 3; ++r) {
            D[r*4+0] = fmaf( c, S[r*4+0], s * S[r*4+1]);
            D[r*4+1] = fmaf(-s, S[r*4+0], c * S[r*4+1]);
            D[r*4+2] = S[r*4+2];
            D[r*4+3] = S[r*4+3];
        }

        // T = T @ D (affine compose, bottom rows implicit).
        float Tn[12];
        #pragma unroll
        for (int r = 0; r < 3; ++r) {
            #pragma unroll
            for (int cI = 0; cI < 4; ++cI) {
                float acc = (cI == 3) ? T[r*4+3] : 0.f;
                acc = fmaf(T[r*4+0], D[0*4+cI], acc);
                acc = fmaf(T[r*4+1], D[1*4+cI], acc);
                acc = fmaf(T[r*4+2], D[2*4+cI], acc);
                Tn[r*4+cI] = acc;
            }
        }
        #pragma unroll
        for (int k = 0; k < 12; ++k) T[k] = Tn[k];

        // Store this joint's 4x4 (16 consecutive floats) as 4x float4.
        float4* p = reinterpret_cast<float4*>(o + j * 16);
        p[0] = make_float4(T[0], T[1], T[2],  T[3]);
        p[1] = make_float4(T[4], T[5], T[6],  T[7]);
        p[2] = make_float4(T[8], T[9], T[10], T[11]);
        p[3] = make_float4(0.f, 0.f, 0.f, 1.f);
    }
}

extern "C" void kernel_launch(void* const* d_in, const int* in_sizes, int n_in,
                              void* d_out, int out_size, void* d_ws, size_t ws_size,
                              hipStream_t stream) {
    const float* eulers = (const float*)d_in[0];
    float* out = (float*)d_out;
    const int B = in_sizes[0] / 7;

    // Host-side double-precision computation of the 7 static transforms
    // (T = Trans(t) @ Rz(yaw) @ Ry(pitch) @ Rx(roll)). Deterministic, tiny,
    // passed by value -> graph-capture safe.
    static const double TRANS[7][3] = {
        { 0.05355, 0.0725,  0.41492},
        { 0.03,    0.0,     0.1    },
        {-0.03,    0.17283, 0.0    },
        {-0.04188, 0.0,     0.07873},
        { 0.0405,  0.16461, 0.0    },
        {-0.027,   0.0,     0.10039},
        { 0.027,   0.029,   0.0    },
    };
    static const double RPY[7][3] = {
        {-0.9795,    -0.5682,    2.3155},
        { 1.5707963,  0.0,       0.0   },
        {-1.5707963,  0.0,       0.0   },
        { 1.5707963, -1.5707963, 0.0   },
        {-1.5707963,  0.0,       0.0   },
        { 1.5707963,  0.0,       0.0   },
        {-1.5707963,  0.0,       0.0   },
    };

    Statics st;
    for (int j = 0; j < 7; ++j) {
        const double r = RPY[j][0], p = RPY[j][1], y = RPY[j][2];
        const double cr = cos(r), sr = sin(r);
        const double cp = cos(p), sp = sin(p);
        const double cy = cos(y), sy = sin(y);
        const double R[3][3] = {
            { cy*cp, cy*sp*sr - sy*cr, cy*sp*cr + sy*sr },
            { sy*cp, sy*sp*sr + cy*cr, sy*sp*cr - cy*sr },
            { -sp,   cp*sr,            cp*cr            },
        };
        for (int rr = 0; rr < 3; ++rr) {
            for (int cc = 0; cc < 3; ++cc) st.m[j][rr*4+cc] = (float)R[rr][cc];
            st.m[j][rr*4+3] = (float)TRANS[j][rr];
        }
    }

    const int grid = (B + 255) / 256;
    hipLaunchKernelGGL(fk_kernel, dim3(grid), dim3(256), 0, stream, eulers, out, st, B);
}

// Round 2
// 29.786 us; speedup vs baseline: 1.6856x; 1.6856x over previous
//
#include <hip/hip_runtime.h>
#include <math.h>

// YUMI left-arm FK: out[b,j] = T_static_0 Rz(a0) ... T_static_j Rz(aj), affine 4x4.
// Memory-bound: 117.4 MB out + 7.3 MB in => ~20 us floor at 6.3 TB/s.
//
// R2 change: outputs staged in LDS, then block-cooperative contiguous float4
// copy-out. R1's direct stores were lane-strided at 448 B -> 64 scattered 16B
// sectors per store instruction -> ~2.5 TB/s effective. Coalesced copy fixes it.

struct Statics { float m[7][12]; };  // 3x4 row-major per joint (bottom row implicit)

#define BT 64          // threads per block == batch elements per block (1 wave)
#define ROW4 28        // float4 per batch element (7 joints * 4 rows)
#define PAD4 29        // padded LDS row stride in float4 (skews banks, keeps 16B align)

__global__ __launch_bounds__(BT) void fk_kernel(
    const float* __restrict__ eulers, float* __restrict__ out,
    Statics st, int B)
{
    __shared__ float  ang[BT * 7];
    __shared__ float4 obuf4[BT * PAD4];   // 29,696 B

    const int b0 = blockIdx.x * BT;
    int nb = B - b0; if (nb > BT) nb = BT;

    // Coalesced staging of input angles into LDS.
    {
        const int nval = nb * 7;
        for (int k = threadIdx.x; k < nval; k += BT)
            ang[k] = eulers[(size_t)b0 * 7 + k];
    }
    __syncthreads();

    const int b = b0 + (int)threadIdx.x;
    if (b < B) {
        const float* a = &ang[threadIdx.x * 7];  // stride 7: odd -> conflict-free
        float4* orow = &obuf4[threadIdx.x * PAD4];

        // Accumulator T: 3x4 affine, init identity.
        float T[12] = {1.f,0.f,0.f,0.f, 0.f,1.f,0.f,0.f, 0.f,0.f,1.f,0.f};

        #pragma unroll
        for (int j = 0; j < 7; ++j) {
            float s, c;
            __sincosf(a[j], &s, &c);
            const float* S = st.m[j];

            // D = S @ Rz(a): only columns 0,1 mix; cols 2,3 pass through.
            float D[12];
            #pragma unroll
            for (int r = 0; r < 3; ++r) {
                D[r*4+0] = fmaf( c, S[r*4+0], s * S[r*4+1]);
                D[r*4+1] = fmaf(-s, S[r*4+0], c * S[r*4+1]);
                D[r*4+2] = S[r*4+2];
                D[r*4+3] = S[r*4+3];
            }

            // T = T @ D (affine compose, bottom rows implicit).
            float Tn[12];
            #pragma unroll
            for (int r = 0; r < 3; ++r) {
                #pragma unroll
                for (int cI = 0; cI < 4; ++cI) {
                    float acc = (cI == 3) ? T[r*4+3] : 0.f;
                    acc = fmaf(T[r*4+0], D[0*4+cI], acc);
                    acc = fmaf(T[r*4+1], D[1*4+cI], acc);
                    acc = fmaf(T[r*4+2], D[2*4+cI], acc);
                    Tn[r*4+cI] = acc;
                }
            }
            #pragma unroll
            for (int k = 0; k < 12; ++k) T[k] = Tn[k];

            // Stage this joint's 4x4 into LDS (ds_write_b128 x4).
            orow[j*4+0] = make_float4(T[0], T[1], T[2],  T[3]);
            orow[j*4+1] = make_float4(T[4], T[5], T[6],  T[7]);
            orow[j*4+2] = make_float4(T[8], T[9], T[10], T[11]);
            orow[j*4+3] = make_float4(0.f, 0.f, 0.f, 1.f);
        }
    }
    __syncthreads();

    // Block-cooperative, fully-coalesced copy-out. Contiguous region:
    // out[b0*112 .. (b0+nb)*112) as float4. LDS index = q + row (pad skew).
    float4* out4 = reinterpret_cast<float4*>(out) + (size_t)b0 * ROW4;
    const int total4 = nb * ROW4;
    if (nb == BT) {
        #pragma unroll 7
        for (int q = threadIdx.x; q < BT * ROW4; q += BT) {
            const int row = q / ROW4;
            out4[q] = obuf4[q + row];
        }
    } else {
        for (int q = threadIdx.x; q < total4; q += BT) {
            const int row = q / ROW4;
            out4[q] = obuf4[q + row];
        }
    }
}

extern "C" void kernel_launch(void* const* d_in, const int* in_sizes, int n_in,
                              void* d_out, int out_size, void* d_ws, size_t ws_size,
                              hipStream_t stream) {
    const float* eulers = (const float*)d_in[0];
    float* out = (float*)d_out;
    const int B = in_sizes[0] / 7;

    // Host-side double-precision static transforms (graph-capture safe kernarg).
    static const double TRANS[7][3] = {
        { 0.05355, 0.0725,  0.41492},
        { 0.03,    0.0,     0.1    },
        {-0.03,    0.17283, 0.0    },
        {-0.04188, 0.0,     0.07873},
        { 0.0405,  0.16461, 0.0    },
        {-0.027,   0.0,     0.10039},
        { 0.027,   0.029,   0.0    },
    };
    static const double RPY[7][3] = {
        {-0.9795,    -0.5682,    2.3155},
        { 1.5707963,  0.0,       0.0   },
        {-1.5707963,  0.0,       0.0   },
        { 1.5707963, -1.5707963, 0.0   },
        {-1.5707963,  0.0,       0.0   },
        { 1.5707963,  0.0,       0.0   },
        {-1.5707963,  0.0,       0.0   },
    };

    Statics st;
    for (int j = 0; j < 7; ++j) {
        const double r = RPY[j][0], p = RPY[j][1], y = RPY[j][2];
        const double cr = cos(r), sr = sin(r);
        const double cp = cos(p), sp = sin(p);
        const double cy = cos(y), sy = sin(y);
        const double R[3][3] = {
            { cy*cp, cy*sp*sr - sy*cr, cy*sp*cr + sy*sr },
            { sy*cp, sy*sp*sr + cy*cr, sy*sp*cr - cy*sr },
            { -sp,   cp*sr,            cp*cr            },
        };
        for (int rr = 0; rr < 3; ++rr) {
            for (int cc = 0; cc < 3; ++cc) st.m[j][rr*4+cc] = (float)R[rr][cc];
            st.m[j][rr*4+3] = (float)TRANS[j][rr];
        }
    }

    const int grid = (B + BT - 1) / BT;
    hipLaunchKernelGGL(fk_kernel, dim3(grid), dim3(BT), 0, stream, eulers, out, st, B);
}

// Round 3
// 24.695 us; speedup vs baseline: 2.0330x; 1.2061x over previous
//
#include <hip/hip_runtime.h>
#include <math.h>

// YUMI left-arm FK: out[b,j] = T_static_0 Rz(a0) ... T_static_j Rz(aj), 4x4.
// Memory-bound: 117.4 MB out + 7.3 MB in => ~18-20 us floor at achieved HBM BW.
//
// R3: row-parallel decomposition. Row r of T_j depends only on row r of
// T_{j-1}  (row_r(A@B) = row_r(A)@B), so 4 lanes per batch element each
// propagate ONE 1x4 row (~16 FMA/joint). Lane r=3 stays (0,0,0,1) for free.
// Stores: each 4-lane group writes one contiguous 64B-aligned segment per
// joint (448 = 7*64) -> sector-dense, no LDS transpose, no barriers,
// ~30 VGPR -> full occupancy. R2's LDS staging capped at 5 waves/CU.

struct Statics { float m[7][12]; };  // 3x4 row-major per joint

#define TPB 256

__global__ __launch_bounds__(TPB) void fk_kernel(
    const float* __restrict__ eulers, float* __restrict__ out,
    Statics st, int B)
{
    const int gid = blockIdx.x * TPB + (int)threadIdx.x;
    const int e = gid >> 2;   // batch element
    const int r = gid & 3;    // output row this lane owns
    if (e >= B) return;

    const float* a = eulers + (size_t)e * 7;

    // Trow = row r of identity.
    float t0 = (r == 0) ? 1.f : 0.f;
    float t1 = (r == 1) ? 1.f : 0.f;
    float t2 = (r == 2) ? 1.f : 0.f;
    float t3 = (r == 3) ? 1.f : 0.f;

    // float4 index: e*28 + r, advancing 4 float4 (=64B) per joint.
    float4* obase = reinterpret_cast<float4*>(out) + (size_t)e * 28 + r;

    #pragma unroll
    for (int j = 0; j < 7; ++j) {
        float s, c;
        __sincosf(a[j], &s, &c);
        const float* S = st.m[j];  // kernarg -> SGPRs

        // D_j = S @ Rz(a): col0 = c*Scol0 + s*Scol1, col1 = -s*Scol0 + c*Scol1,
        // cols 2,3 pass through; bottom row (0,0,0,1).
        // Trow_new = Trow @ D_j, factored so the rotation applies AFTER the
        // static contraction (u = Trow.Scol0, v = Trow.Scol1):
        const float u  = fmaf(t0, S[0], fmaf(t1, S[4], t2 * S[8]));
        const float v  = fmaf(t0, S[1], fmaf(t1, S[5], t2 * S[9]));
        const float n2 = fmaf(t0, S[2], fmaf(t1, S[6], t2 * S[10]));
        const float n3 = fmaf(t0, S[3], fmaf(t1, S[7], fmaf(t2, S[11], t3)));
        t0 = fmaf(c, u, s * v);
        t1 = fmaf(c, v, -s * u);
        t2 = n2;
        t3 = n3;

        obase[j * 4] = make_float4(t0, t1, t2, t3);
    }
}

extern "C" void kernel_launch(void* const* d_in, const int* in_sizes, int n_in,
                              void* d_out, int out_size, void* d_ws, size_t ws_size,
                              hipStream_t stream) {
    const float* eulers = (const float*)d_in[0];
    float* out = (float*)d_out;
    const int B = in_sizes[0] / 7;

    // Host-side double-precision static transforms (graph-capture-safe kernarg).
    static const double TRANS[7][3] = {
        { 0.05355, 0.0725,  0.41492},
        { 0.03,    0.0,     0.1    },
        {-0.03,    0.17283, 0.0    },
        {-0.04188, 0.0,     0.07873},
        { 0.0405,  0.16461, 0.0    },
        {-0.027,   0.0,     0.10039},
        { 0.027,   0.029,   0.0    },
    };
    static const double RPY[7][3] = {
        {-0.9795,    -0.5682,    2.3155},
        { 1.5707963,  0.0,       0.0   },
        {-1.5707963,  0.0,       0.0   },
        { 1.5707963, -1.5707963, 0.0   },
        {-1.5707963,  0.0,       0.0   },
        { 1.5707963,  0.0,       0.0   },
        {-1.5707963,  0.0,       0.0   },
    };

    Statics st;
    for (int j = 0; j < 7; ++j) {
        const double r = RPY[j][0], p = RPY[j][1], y = RPY[j][2];
        const double cr = cos(r), sr = sin(r);
        const double cp = cos(p), sp = sin(p);
        const double cy = cos(y), sy = sin(y);
        const double R[3][3] = {
            { cy*cp, cy*sp*sr - sy*cr, cy*sp*cr + sy*sr },
            { sy*cp, sy*sp*sr + cy*cr, sy*sp*cr - cy*sr },
            { -sp,   cp*sr,            cp*cr            },
        };
        for (int rr = 0; rr < 3; ++rr) {
            for (int cc = 0; cc < 3; ++cc) st.m[j][rr*4+cc] = (float)R[rr][cc];
            st.m[j][rr*4+3] = (float)TRANS[j][rr];
        }
    }

    const long long threads = (long long)B * 4;
    const int grid = (int)((threads + TPB - 1) / TPB);
    hipLaunchKernelGGL(fk_kernel, dim3(grid), dim3(TPB), 0, stream, eulers, out, st, B);
}